// Round 14
// baseline (945.154 us; speedup 1.0000x reference)
//
#include <hip/hip_runtime.h>

#define NV 50000
#define NE 800000
#define NB 8
#define NH 128
#define NLAT 64
#define NTD 16
#define NL 4
#define SK 136   // LDS row stride (bf16 elems) for MFMA A tiles
#define SKB 136  // LDS row stride (bytes) for fp8 hid tile in k_edge
#define MTB 132  // LDS stride (bytes) for transposed fp8 m tile

typedef __attribute__((ext_vector_type(8))) short short8;
typedef __attribute__((ext_vector_type(4))) float f32x4;
typedef __attribute__((ext_vector_type(2))) float f32x2;

__device__ __forceinline__ float silu_f(float x){
    float e = __expf(-x);
    return x * __builtin_amdgcn_rcpf(1.0f + e);
}

// HW packed f32->bf16 convert (RNE)
__device__ __forceinline__ unsigned cvtpk(float a, float b){
    unsigned r;
    asm("v_cvt_pk_bf16_f32 %0, %1, %2" : "=v"(r) : "v"(a), "v"(b));
    return r;
}
__device__ __forceinline__ unsigned short f2bf_fast(float x){
    return (unsigned short)cvtpk(x, x);
}
// bit-twiddle fallback for one-shot pack kernel
__device__ __forceinline__ unsigned short f2bf(float x){
    unsigned u = __float_as_uint(x);
    unsigned r = (u >> 16) & 1;
    u += 0x7fffu + r;
    return (unsigned short)(u >> 16);
}
__device__ __forceinline__ float bflo(unsigned u){ return __uint_as_float(u << 16); }
__device__ __forceinline__ float bfhi(unsigned u){ return __uint_as_float(u & 0xffff0000u); }

// 32 bf16 (LDS, 16B aligned) -> 32 fp8 bytes at dstg (global)
__device__ __forceinline__ void bf16row_to_fp8(const unsigned short* src, unsigned char* dstg){
    unsigned ow[8];
    #pragma unroll
    for (int c = 0; c < 8; c++){
        uint2 uu = *(const uint2*)(src + c*4);
        unsigned w = __builtin_amdgcn_cvt_pk_fp8_f32(bflo(uu.x), bfhi(uu.x), 0, false);
        w = __builtin_amdgcn_cvt_pk_fp8_f32(bflo(uu.y), bfhi(uu.y), w, true);
        ow[c] = w;
    }
    uint4 o0, o1;
    o0.x = ow[0]; o0.y = ow[1]; o0.z = ow[2]; o0.w = ow[3];
    o1.x = ow[4]; o1.y = ow[5]; o1.z = ow[6]; o1.w = ow[7];
    *(uint4*)(dstg)      = o0;
    *(uint4*)(dstg + 16) = o1;
}

// ---------------- setup ----------------
__global__ void k_setup(const float* __restrict__ z, const float* __restrict__ t,
                        const float* __restrict__ te_w1, const float* __restrict__ te_b1,
                        const float* __restrict__ te_w2, const float* __restrict__ te_b2,
                        const float* __restrict__ cp_w, const float* __restrict__ cp_b,
                        float* __restrict__ tconst, float* __restrict__ zcp)
{
    __shared__ float hid[NTD];
    __shared__ float emb[NTD];
    int tid = threadIdx.x;
    float ts = t[0];
    if (tid < NTD) hid[tid] = silu_f(ts * te_w1[tid] + te_b1[tid]);
    __syncthreads();
    if (tid < NTD){
        float a = te_b2[tid];
        for (int j = 0; j < NTD; j++) a += hid[j] * te_w2[j*NTD + tid];
        emb[tid] = a;
    }
    __syncthreads();
    float tc = cp_b[tid];
    for (int j = 0; j < NTD; j++) tc += emb[j] * cp_w[(NLAT + j)*NH + tid];
    tconst[tid] = tc;
    for (int b = 0; b < NB; b++){
        float a = 0.f;
        for (int k = 0; k < NLAT; k++) a += z[b*NLAT + k] * cp_w[k*NH + tid];
        zcp[b*NH + tid] = a;
    }
}

__global__ void k_init(const int* __restrict__ batch, const float* __restrict__ zcp,
                       const float* __restrict__ tconst, float* __restrict__ h)
{
    int idx = blockIdx.x*256 + threadIdx.x;
    int v = idx >> 7, d = idx & 127;
    h[idx] = zcp[batch[v]*NH + d] + tconst[d];
}

__global__ void k_xt(const float* __restrict__ pos0, const float* __restrict__ pos1,
                     const float* __restrict__ t, float* __restrict__ xt)
{
    int idx = blockIdx.x*256 + threadIdx.x;
    if (idx < NV*3){
        float ts = t[0];
        xt[idx] = (1.f - ts)*pos0[idx] + ts*pos1[idx];
    }
}

// ---------------- CSR build ----------------
__global__ void k_hist(const int* __restrict__ dst, int* __restrict__ cnt)
{
    int e = blockIdx.x*256 + threadIdx.x;
    if (e < NE) atomicAdd(&cnt[dst[e]], 1);
}

__global__ void k_scan1(const int* __restrict__ deg, int* __restrict__ bsum)
{
    __shared__ int s[256];
    int tid = threadIdx.x;
    int idx = blockIdx.x*256 + tid;
    s[tid] = (idx < NV) ? deg[idx] : 0;
    __syncthreads();
    for (int off = 128; off > 0; off >>= 1){
        if (tid < off) s[tid] += s[tid + off];
        __syncthreads();
    }
    if (tid == 0) bsum[blockIdx.x] = s[0];
}

__global__ void k_scan2(int* __restrict__ bsum)
{
    __shared__ int s[256];
    int tid = threadIdx.x;
    int v = (tid < 196) ? bsum[tid] : 0;
    s[tid] = v;
    __syncthreads();
    for (int off = 1; off < 256; off <<= 1){
        int a = s[tid];
        int b = (tid >= off) ? s[tid - off] : 0;
        __syncthreads();
        s[tid] = a + b;
        __syncthreads();
    }
    if (tid < 196) bsum[tid] = (tid == 0) ? 0 : s[tid - 1];
}

__global__ void k_scan3(const int* deg, const int* __restrict__ bsum,
                        int* __restrict__ rowptr, int* cursor)
{
    __shared__ int s[256];
    int tid = threadIdx.x;
    int idx = blockIdx.x*256 + tid;
    int v = (idx < NV) ? deg[idx] : 0;
    s[tid] = v;
    __syncthreads();
    for (int off = 1; off < 256; off <<= 1){
        int a = s[tid];
        int b = (tid >= off) ? s[tid - off] : 0;
        __syncthreads();
        s[tid] = a + b;
        __syncthreads();
    }
    int excl = bsum[blockIdx.x] + ((tid == 0) ? 0 : s[tid - 1]);
    if (idx < NV){
        rowptr[idx] = excl;
        cursor[idx] = excl;
    }
    if (idx == NV - 1) rowptr[NV] = NE;
}

__global__ void k_scatter(const int* __restrict__ dst, int* __restrict__ cursor,
                          int* __restrict__ csr_eid, int* __restrict__ csr_dst)
{
    int e = blockIdx.x*256 + threadIdx.x;
    if (e < NE){
        int i = dst[e];
        int p = atomicAdd(&cursor[i], 1);
        csr_eid[p] = e;
        csr_dst[p] = i;
    }
}

// ---------------- pack weights -> bf16 [l][{eWd,eWs,eW2,nW1d,nW1a,nW2}][n][k] ----------------
__global__ void k_pack_wpk(const float* __restrict__ ew1, const float* __restrict__ ew2,
                           const float* __restrict__ nw1, const float* __restrict__ nw2,
                           unsigned short* __restrict__ wpk)
{
    int idx = blockIdx.x*256 + threadIdx.x;
    int lm = idx >> 14;
    int l = lm / 6, m = lm % 6;
    int r = idx & 16383;
    int n = r >> 7, k = r & 127;
    float v;
    if (m < 2)       v = ew1[l*33152 + (m*128 + k)*128 + n];
    else if (m == 2) v = ew2[l*16384 + k*128 + n];
    else if (m < 5)  v = nw1[l*32768 + ((m-3)*128 + k)*128 + n];
    else             v = nw2[l*16384 + k*128 + n];
    wpk[idx] = f2bf(v);
}

// ---------------- pack W2 -> fp8 [l][n][k] ----------------
__global__ void k_pack_w2f8(const float* __restrict__ ew2, unsigned char* __restrict__ w2f8)
{
    int idx = blockIdx.x*256 + threadIdx.x;        // 4*16384
    int l = idx >> 14, r = idx & 16383;
    int n = r >> 7, k = r & 127;
    float v = ew2[l*16384 + k*128 + n];
    w2f8[idx] = (unsigned char)__builtin_amdgcn_cvt_pk_fp8_f32(v, v, 0, false);
}

// ---------------- layer-0 pre-projection (MFMA, sequential branches; d->bf16, s->fp8; zeroes agg) ----------------
__global__ __launch_bounds__(256) void k_pre_mfma(
    const float* __restrict__ h, const float* __restrict__ xt,
    const unsigned short* __restrict__ wpk_l,   // Wd at +0, Ws at +16384
    const float* __restrict__ w1c, const float* __restrict__ b1,
    unsigned short* __restrict__ pre_di, unsigned char* __restrict__ pre_sj,
    float* __restrict__ agg)
{
    __shared__ __align__(16) unsigned short asd[64*SK];    // A tile (stays intact)
    __shared__ __align__(16) unsigned short obuf[64*SK];   // per-branch output tile
    __shared__ float xts[64*4];
    int tid = threadIdx.x;
    int tile0 = blockIdx.x*64;

    {
        int r = tid >> 2, dq = tid & 3;
        int node = tile0 + r;
        bool valid = node < NV;
        const float4* hrow = (const float4*)(h + (size_t)node*NH + dq*32);
        #pragma unroll
        for (int c = 0; c < 4; c++){
            float4 v0 = valid ? hrow[c*2]     : make_float4(0.f,0.f,0.f,0.f);
            float4 v1 = valid ? hrow[c*2 + 1] : make_float4(0.f,0.f,0.f,0.f);
            uint4 o;
            o.x = cvtpk(v0.x, v0.y);
            o.y = cvtpk(v0.z, v0.w);
            o.z = cvtpk(v1.x, v1.y);
            o.w = cvtpk(v1.z, v1.w);
            *(uint4*)&asd[r*SK + dq*32 + c*8] = o;
        }
        if (valid){
            float4 z4 = make_float4(0.f,0.f,0.f,0.f);
            float* ag = agg + (size_t)node*NH + dq*32;
            #pragma unroll
            for (int c = 0; c < 8; c++) *(float4*)(ag + c*4) = z4;
        }
    }
    if (tid < 64){
        int node = tile0 + tid;
        bool valid = node < NV;
        xts[tid*4+0] = valid ? xt[node*3+0] : 0.f;
        xts[tid*4+1] = valid ? xt[node*3+1] : 0.f;
        xts[tid*4+2] = valid ? xt[node*3+2] : 0.f;
        xts[tid*4+3] = 0.f;
    }

    int w = tid >> 6, l = tid & 63;
    int lr = l & 15, lq = l >> 4;

    __syncthreads();

    // ---- branch d ----
    {
        short8 bfr[2][4];
        #pragma unroll
        for (int nt = 0; nt < 2; nt++)
            #pragma unroll
            for (int kc = 0; kc < 4; kc++)
                bfr[nt][kc] = *(const short8*)(wpk_l + (w*32 + nt*16 + lr)*128 + kc*32 + lq*8);
        f32x4 acc[4][2];
        #pragma unroll
        for (int mt = 0; mt < 4; mt++)
            #pragma unroll
            for (int nt = 0; nt < 2; nt++) acc[mt][nt] = (f32x4){0.f,0.f,0.f,0.f};
        #pragma unroll
        for (int kc = 0; kc < 4; kc++)
            #pragma unroll
            for (int mt = 0; mt < 4; mt++){
                short8 af = *(const short8*)&asd[(mt*16 + lr)*SK + kc*32 + lq*8];
                #pragma unroll
                for (int nt = 0; nt < 2; nt++)
                    acc[mt][nt] = __builtin_amdgcn_mfma_f32_16x16x32_bf16(af, bfr[nt][kc], acc[mt][nt], 0, 0, 0);
            }
        #pragma unroll
        for (int nt = 0; nt < 2; nt++){
            int col = w*32 + nt*16 + lr;
            float c0 = w1c[col], c1 = w1c[128 + col], c2 = w1c[256 + col];
            float bb = b1[col];
            #pragma unroll
            for (int mt = 0; mt < 4; mt++)
                #pragma unroll
                for (int r = 0; r < 4; r++){
                    int row = mt*16 + lq*4 + r;
                    float qv = xts[row*4+0]*c0 + xts[row*4+1]*c1 + xts[row*4+2]*c2;
                    obuf[row*SK + col] = f2bf_fast(acc[mt][nt][r] + qv + bb);
                }
        }
    }
    __syncthreads();
    {
        int r = tid >> 2, dq = tid & 3;
        int node = tile0 + r;
        if (node < NV){
            #pragma unroll
            for (int c = 0; c < 4; c++){
                uint4 vd = *(const uint4*)&obuf[r*SK + dq*32 + c*8];
                *(uint4*)(pre_di + (size_t)node*NH + dq*32 + c*8) = vd;
            }
        }
    }

    // ---- branch s ----
    {
        short8 bfr[2][4];
        #pragma unroll
        for (int nt = 0; nt < 2; nt++)
            #pragma unroll
            for (int kc = 0; kc < 4; kc++)
                bfr[nt][kc] = *(const short8*)(wpk_l + 16384 + (w*32 + nt*16 + lr)*128 + kc*32 + lq*8);
        f32x4 acc[4][2];
        #pragma unroll
        for (int mt = 0; mt < 4; mt++)
            #pragma unroll
            for (int nt = 0; nt < 2; nt++) acc[mt][nt] = (f32x4){0.f,0.f,0.f,0.f};
        #pragma unroll
        for (int kc = 0; kc < 4; kc++)
            #pragma unroll
            for (int mt = 0; mt < 4; mt++){
                short8 af = *(const short8*)&asd[(mt*16 + lr)*SK + kc*32 + lq*8];
                #pragma unroll
                for (int nt = 0; nt < 2; nt++)
                    acc[mt][nt] = __builtin_amdgcn_mfma_f32_16x16x32_bf16(af, bfr[nt][kc], acc[mt][nt], 0, 0, 0);
            }
        __syncthreads();   // prior obuf store-reads done
        #pragma unroll
        for (int nt = 0; nt < 2; nt++){
            int col = w*32 + nt*16 + lr;
            float c0 = w1c[col], c1 = w1c[128 + col], c2 = w1c[256 + col];
            #pragma unroll
            for (int mt = 0; mt < 4; mt++)
                #pragma unroll
                for (int r = 0; r < 4; r++){
                    int row = mt*16 + lq*4 + r;
                    float qv = xts[row*4+0]*c0 + xts[row*4+1]*c1 + xts[row*4+2]*c2;
                    obuf[row*SK + col] = f2bf_fast(acc[mt][nt][r] - qv);
                }
        }
    }
    __syncthreads();
    {
        int r = tid >> 2, dq = tid & 3;
        int node = tile0 + r;
        if (node < NV){
            bf16row_to_fp8(&obuf[r*SK + dq*32], pre_sj + (size_t)node*NH + dq*32);
        }
    }
}

// ---------------- fused edge kernel: 128-edge tiles; fp8; 2 col passes (32 AGPR) ----------------
__global__ __launch_bounds__(256) void k_edge_mfma(
    const unsigned short* __restrict__ pre_di, const unsigned char* __restrict__ pre_sj,
    const int* __restrict__ csr_eid, const int* __restrict__ csr_dst,
    const int* __restrict__ srcrow, const int* __restrict__ rowptr,
    const unsigned char* __restrict__ w2f8,   // [n][k] fp8
    const float* __restrict__ b2,
    float* __restrict__ agg)
{
    __shared__ __align__(16) unsigned char hids8[128*SKB];  // 17.4 KB fp8 hid tile
    __shared__ __align__(16) unsigned char m_t[128*MTB];    // 16.9 KB fp8 m tile (transposed)
    __shared__ int nid[128];
    __shared__ int flagL, flagR;
    __shared__ unsigned long long brk0_s, brk1_s;
    int tid = threadIdx.x;

    int b = blockIdx.x;
    int mapped = (b < 6248) ? ((b & 7)*781 + (b >> 3)) : b;
    int p0 = mapped * 128;

    if (tid == 0){
        flagL = (rowptr[csr_dst[p0]] < p0) ? 1 : 0;
        flagR = (rowptr[csr_dst[p0 + 127] + 1] > p0 + 128) ? 1 : 0;
    }

    // hid phase: di bf16 + sj fp8 -> silu -> fp8 LDS
    #pragma unroll
    for (int sub = 0; sub < 2; sub++){
        int el = sub*64 + (tid >> 2), q = tid & 3;
        int p = p0 + el;
        int eid = csr_eid[p];
        int iN  = csr_dst[p];
        int jN  = srcrow[eid];
        if (q == 0) nid[el] = iN;
        const uint4* gd = (const uint4*)(pre_di + (size_t)iN*NH + q*32);
        const uint4* gs = (const uint4*)(pre_sj + (size_t)jN*NH + q*32);
        uint4 s0 = gs[0], s1 = gs[1];
        unsigned sw[8] = {s0.x, s0.y, s0.z, s0.w, s1.x, s1.y, s1.z, s1.w};
        #pragma unroll
        for (int c = 0; c < 4; c++){
            uint4 a = gd[c];
            unsigned au[4] = {a.x, a.y, a.z, a.w};
            f32x2 pa = __builtin_amdgcn_cvt_pk_f32_fp8(sw[c*2],   false);
            f32x2 pb = __builtin_amdgcn_cvt_pk_f32_fp8(sw[c*2],   true);
            f32x2 pc = __builtin_amdgcn_cvt_pk_f32_fp8(sw[c*2+1], false);
            f32x2 pd = __builtin_amdgcn_cvt_pk_f32_fp8(sw[c*2+1], true);
            float sv[8] = {pa.x, pa.y, pb.x, pb.y, pc.x, pc.y, pd.x, pd.y};
            float lo0 = silu_f(bflo(au[0]) + sv[0]);
            float hi0 = silu_f(bfhi(au[0]) + sv[1]);
            float lo1 = silu_f(bflo(au[1]) + sv[2]);
            float hi1 = silu_f(bfhi(au[1]) + sv[3]);
            float lo2 = silu_f(bflo(au[2]) + sv[4]);
            float hi2 = silu_f(bfhi(au[2]) + sv[5]);
            float lo3 = silu_f(bflo(au[3]) + sv[6]);
            float hi3 = silu_f(bfhi(au[3]) + sv[7]);
            unsigned w0 = __builtin_amdgcn_cvt_pk_fp8_f32(lo0, hi0, 0, false);
            w0 = __builtin_amdgcn_cvt_pk_fp8_f32(lo1, hi1, w0, true);
            unsigned w1 = __builtin_amdgcn_cvt_pk_fp8_f32(lo2, hi2, 0, false);
            w1 = __builtin_amdgcn_cvt_pk_fp8_f32(lo3, hi3, w1, true);
            uint2 o; o.x = w0; o.y = w1;
            *(uint2*)&hids8[el*SKB + q*32 + c*8] = o;
        }
    }

    int w = tid >> 6, l = tid & 63;
    int lr = l & 15, lq = l >> 4;

    __syncthreads();

    if (tid < 64){
        bool bb = (tid > 0) && (nid[tid] != nid[tid - 1]);
        unsigned long long mask = __ballot(bb);
        if (tid == 0) brk0_s = mask;
    } else if (tid < 128){
        int lane = tid - 64;
        bool bb = (nid[64 + lane] != nid[63 + lane]);
        unsigned long long mask = __ballot(bb);
        if (lane == 0) brk1_s = mask;
    }

    // two column passes, 32 AGPRs each, B frags loaded per pass
    #pragma unroll
    for (int pass = 0; pass < 2; pass++){
        long bfr[4];
        #pragma unroll
        for (int kc = 0; kc < 4; kc++)
            bfr[kc] = *(const long*)(w2f8 + (pass*64 + w*16 + lr)*128 + kc*32 + lq*8);
        f32x4 acc[8];
        #pragma unroll
        for (int mt = 0; mt < 8; mt++) acc[mt] = (f32x4){0.f,0.f,0.f,0.f};
        #pragma unroll
        for (int kc = 0; kc < 4; kc++){
            #pragma unroll
            for (int mt = 0; mt < 8; mt++){
                long af = *(const long*)&hids8[(mt*16 + lr)*SKB + kc*32 + lq*8];
                acc[mt] = __builtin_amdgcn_mfma_f32_16x16x32_fp8_fp8(af, bfr[kc], acc[mt], 0, 0, 0);
            }
        }
        int col = pass*64 + w*16 + lr;
        float bv = b2[col];
        #pragma unroll
        for (int mt = 0; mt < 8; mt++){
            float v0 = silu_f(acc[mt][0] + bv);
            float v1 = silu_f(acc[mt][1] + bv);
            float v2 = silu_f(acc[mt][2] + bv);
            float v3 = silu_f(acc[mt][3] + bv);
            unsigned wv = __builtin_amdgcn_cvt_pk_fp8_f32(v0, v1, 0, false);
            wv = __builtin_amdgcn_cvt_pk_fp8_f32(v2, v3, wv, true);
            *(unsigned*)&m_t[col*MTB + mt*16 + lq*4] = wv;
        }
    }
    __syncthreads();

    {
        int half = tid >> 7, d = tid & 127;
        int r0 = half * 64;
        bool junc = !((brk1_s) & 1ull);
        unsigned long long m2 = half ? (brk1_s & ~1ull) : brk0_s;
        bool leftCont  = half ? junc : (flagL != 0);
        bool rightCont = half ? (flagR != 0) : junc;

        float run = 0.f;
        int curn = nid[r0];
        bool firstRun = true;
        const unsigned char* mrow = m_t + d*MTB;

        #pragma unroll
        for (int g = 0; g < 16; g++){
            int row = r0 + g*4;
            unsigned v = *(const unsigned*)&mrow[row];
            f32x2 pa = __builtin_amdgcn_cvt_pk_f32_fp8(v, false);
            f32x2 pb = __builtin_amdgcn_cvt_pk_f32_fp8(v, true);
            float f0 = pa.x, f1 = pa.y, f2 = pb.x, f3 = pb.y;
            unsigned gm = (unsigned)((m2 >> (g*4)) & 0xFull);
            if (gm == 0u){
                run += (f0 + f1) + (f2 + f3);
            } else {
                float fv[4] = {f0, f1, f2, f3};
                #pragma unroll
                for (int r = 0; r < 4; r++){
                    if (gm & (1u << r)){
                        bool at = firstRun && leftCont;
                        if (at) atomicAdd(&agg[(size_t)curn*NH + d], run);
                        else    agg[(size_t)curn*NH + d] = run;
                        firstRun = false;
                        run = 0.f;
                        curn = nid[row + r];
                    }
                    run += fv[r];
                }
            }
        }
        bool at = (firstRun && leftCont) || rightCont;
        if (at) atomicAdd(&agg[(size_t)curn*NH + d], run);
        else    agg[(size_t)curn*NH + d] = run;
    }
}

// ---------------- fused node kernel: LN(h + MLP([h|agg])) then next-layer pre (sequential branches) ----------------
__global__ __launch_bounds__(256) void k_node_fused(
    float* __restrict__ h, float* __restrict__ agg,
    const unsigned short* __restrict__ wn,   // node weights: W1d, W1a, W2
    const float* __restrict__ b1, const float* __restrict__ b2,
    const float* __restrict__ g, const float* __restrict__ bta,
    const float* __restrict__ xt,
    const unsigned short* __restrict__ wpk_next,   // next-layer eWd at +0, eWs at +16384
    const float* __restrict__ w1c_next, const float* __restrict__ b1_next,
    unsigned short* __restrict__ pre_di, unsigned char* __restrict__ pre_sj,
    int do_pre)
{
    __shared__ __align__(16) unsigned short abuf[2*64*SK];
    __shared__ float ps[64][4], pq[64][4];
    __shared__ float mu_s[64], rs_s[64];
    __shared__ float xts[64*4];
    int tid = threadIdx.x;
    int tile0 = blockIdx.x*64;
    unsigned short* a1 = abuf;
    unsigned short* a2 = abuf + 64*SK;

    {
        int r = tid >> 2, dq = tid & 3;
        int node = tile0 + r;
        bool valid = node < NV;
        const float4* hrow = (const float4*)(h   + (size_t)node*NH + dq*32);
        const float4* arow = (const float4*)(agg + (size_t)node*NH + dq*32);
        #pragma unroll
        for (int c = 0; c < 4; c++){
            float4 v0 = valid ? hrow[c*2]     : make_float4(0.f,0.f,0.f,0.f);
            float4 v1 = valid ? hrow[c*2 + 1] : make_float4(0.f,0.f,0.f,0.f);
            float4 u0 = valid ? arow[c*2]     : make_float4(0.f,0.f,0.f,0.f);
            float4 u1 = valid ? arow[c*2 + 1] : make_float4(0.f,0.f,0.f,0.f);
            uint4 o;
            o.x = cvtpk(v0.x, v0.y); o.y = cvtpk(v0.z, v0.w);
            o.z = cvtpk(v1.x, v1.y); o.w = cvtpk(v1.z, v1.w);
            *(uint4*)&a1[r*SK + dq*32 + c*8] = o;
            uint4 p;
            p.x = cvtpk(u0.x, u0.y); p.y = cvtpk(u0.z, u0.w);
            p.z = cvtpk(u1.x, u1.y); p.w = cvtpk(u1.z, u1.w);
            *(uint4*)&a2[r*SK + dq*32 + c*8] = p;
        }
        if (do_pre && valid){
            float4 z4 = make_float4(0.f,0.f,0.f,0.f);
            float* ag = agg + (size_t)node*NH + dq*32;
            #pragma unroll
            for (int c = 0; c < 8; c++) *(float4*)(ag + c*4) = z4;
        }
    }
    if (tid < 64){
        int node = tile0 + tid;
        bool valid = node < NV;
        xts[tid*4+0] = valid ? xt[node*3+0] : 0.f;
        xts[tid*4+1] = valid ? xt[node*3+1] : 0.f;
        xts[tid*4+2] = valid ? xt[node*3+2] : 0.f;
        xts[tid*4+3] = 0.f;
    }

    int w = tid >> 6, l = tid & 63;
    int lr = l & 15, lq = l >> 4;
    int colb = w*32;

    __syncthreads();

    f32x4 acc[4][2];
    #pragma unroll
    for (int mt = 0; mt < 4; mt++)
        #pragma unroll
        for (int nt = 0; nt < 2; nt++) acc[mt][nt] = (f32x4){0.f,0.f,0.f,0.f};

    {
        short8 bfr[2][4];
        #pragma unroll
        for (int nt = 0; nt < 2; nt++)
            #pragma unroll
            for (int kc = 0; kc < 4; kc++)
                bfr[nt][kc] = *(const short8*)(wn + (colb + nt*16 + lr)*128 + kc*32 + lq*8);
        #pragma unroll
        for (int kc = 0; kc < 4; kc++)
            #pragma unroll
            for (int mt = 0; mt < 4; mt++){
                short8 af = *(const short8*)&a1[(mt*16 + lr)*SK + kc*32 + lq*8];
                #pragma unroll
                for (int nt = 0; nt < 2; nt++)
                    acc[mt][nt] = __builtin_amdgcn_mfma_f32_16x16x32_bf16(af, bfr[nt][kc], acc[mt][nt], 0, 0, 0);
            }
    }
    {
        short8 bfr[2][4];
        #pragma unroll
        for (int nt = 0; nt < 2; nt++)
            #pragma unroll
            for (int kc = 0; kc < 4; kc++)
                bfr[nt][kc] = *(const short8*)(wn + 16384 + (colb + nt*16 + lr)*128 + kc*32 + lq*8);
        #pragma unroll
        for (int kc = 0; kc < 4; kc++)
            #pragma unroll
            for (int mt = 0; mt < 4; mt++){
                short8 af = *(const short8*)&a2[(mt*16 + lr)*SK + kc*32 + lq*8];
                #pragma unroll
                for (int nt = 0; nt < 2; nt++)
                    acc[mt][nt] = __builtin_amdgcn_mfma_f32_16x16x32_bf16(af, bfr[nt][kc], acc[mt][nt], 0, 0, 0);
            }
    }
    __syncthreads();

    #pragma unroll
    for (int nt = 0; nt < 2; nt++){
        int col = colb + nt*16 + lr;
        float bv = b1[col];
        #pragma unroll
        for (int mt = 0; mt < 4; mt++)
            #pragma unroll
            for (int r = 0; r < 4; r++){
                int row = mt*16 + lq*4 + r;
                a1[row*SK + col] = f2bf_fast(silu_f(acc[mt][nt][r] + bv));
            }
    }
    __syncthreads();

    f32x4 acc2[4][2];
    #pragma unroll
    for (int mt = 0; mt < 4; mt++)
        #pragma unroll
        for (int nt = 0; nt < 2; nt++) acc2[mt][nt] = (f32x4){0.f,0.f,0.f,0.f};
    {
        short8 bfr[2][4];
        #pragma unroll
        for (int nt = 0; nt < 2; nt++)
            #pragma unroll
            for (int kc = 0; kc < 4; kc++)
                bfr[nt][kc] = *(const short8*)(wn + 2*16384 + (colb + nt*16 + lr)*128 + kc*32 + lq*8);
        #pragma unroll
        for (int kc = 0; kc < 4; kc++)
            #pragma unroll
            for (int mt = 0; mt < 4; mt++){
                short8 af = *(const short8*)&a1[(mt*16 + lr)*SK + kc*32 + lq*8];
                #pragma unroll
                for (int nt = 0; nt < 2; nt++)
                    acc2[mt][nt] = __builtin_amdgcn_mfma_f32_16x16x32_bf16(af, bfr[nt][kc], acc2[mt][nt], 0, 0, 0);
            }
    }
    __syncthreads();

    float* xls = (float*)abuf;
    #pragma unroll
    for (int nt = 0; nt < 2; nt++){
        int col = colb + nt*16 + lr;
        float bv = b2[col];
        #pragma unroll
        for (int mt = 0; mt < 4; mt++)
            #pragma unroll
            for (int r = 0; r < 4; r++){
                int row = mt*16 + lq*4 + r;
                int node = tile0 + row;
                float hv = (node < NV) ? h[(size_t)node*NH + col] : 0.f;
                xls[row*132 + col] = hv + acc2[mt][nt][r] + bv;
            }
    }
    __syncthreads();

    {
        int r = tid >> 2, part = tid & 3;
        float s = 0.f, q = 0.f;
        #pragma unroll 8
        for (int i = 0; i < 32; i++){
            float x = xls[r*132 + part*32 + i];
            s += x; q += x*x;
        }
        ps[r][part] = s; pq[r][part] = q;
    }
    __syncthreads();
    if (tid < 64){
        float s = ps[tid][0] + ps[tid][1] + ps[tid][2] + ps[tid][3];
        float q = pq[tid][0] + pq[tid][1] + pq[tid][2] + pq[tid][3];
        float mu = s * (1.f/128.f);
        float var = q * (1.f/128.f) - mu*mu;
        mu_s[tid] = mu;
        rs_s[tid] = rsqrtf(var + 1e-5f);
    }
    __syncthreads();

    float ovals[32];
    {
        int r = tid >> 2, part = tid & 3;
        int node = tile0 + r;
        float mu = mu_s[r], rs = rs_s[r];
        #pragma unroll
        for (int c = 0; c < 8; c++){
            int d = part*32 + c*4;
            float4 o;
            o.x = g[d+0]*(xls[r*132 + d+0] - mu)*rs + bta[d+0];
            o.y = g[d+1]*(xls[r*132 + d+1] - mu)*rs + bta[d+1];
            o.z = g[d+2]*(xls[r*132 + d+2] - mu)*rs + bta[d+2];
            o.w = g[d+3]*(xls[r*132 + d+3] - mu)*rs + bta[d+3];
            ovals[c*4+0] = o.x; ovals[c*4+1] = o.y;
            ovals[c*4+2] = o.z; ovals[c*4+3] = o.w;
            if (node < NV) *(float4*)(h + (size_t)node*NH + d) = o;
        }
    }

    if (!do_pre) return;

    __syncthreads();   // all xls reads done -> abuf reusable
    // pack LN result -> a1 (bf16 A-tile)
    {
        int r = tid >> 2, part = tid & 3;
        #pragma unroll
        for (int c = 0; c < 4; c++){
            uint4 o;
            o.x = cvtpk(ovals[c*8+0], ovals[c*8+1]);
            o.y = cvtpk(ovals[c*8+2], ovals[c*8+3]);
            o.z = cvtpk(ovals[c*8+4], ovals[c*8+5]);
            o.w = cvtpk(ovals[c*8+6], ovals[c*8+7]);
            *(uint4*)&a1[r*SK + part*32 + c*8] = o;
        }
    }
    __syncthreads();

    // ---- branch d ----
    {
        short8 bfr[2][4];
        #pragma unroll
        for (int nt = 0; nt < 2; nt++)
            #pragma unroll
            for (int kc = 0; kc < 4; kc++)
                bfr[nt][kc] = *(const short8*)(wpk_next + (colb + nt*16 + lr)*128 + kc*32 + lq*8);
        f32x4 accp[4][2];
        #pragma unroll
        for (int mt = 0; mt < 4; mt++)
            #pragma unroll
            for (int nt = 0; nt < 2; nt++) accp[mt][nt] = (f32x4){0.f,0.f,0.f,0.f};
        #pragma unroll
        for (int kc = 0; kc < 4; kc++)
            #pragma unroll
            for (int mt = 0; mt < 4; mt++){
                short8 af = *(const short8*)&a1[(mt*16 + lr)*SK + kc*32 + lq*8];
                #pragma unroll
                for (int nt = 0; nt < 2; nt++)
                    accp[mt][nt] = __builtin_amdgcn_mfma_f32_16x16x32_bf16(af, bfr[nt][kc], accp[mt][nt], 0, 0, 0);
            }
        #pragma unroll
        for (int nt = 0; nt < 2; nt++){
            int col = colb + nt*16 + lr;
            float c0 = w1c_next[col], c1 = w1c_next[128 + col], c2 = w1c_next[256 + col];
            float bb = b1_next[col];
            #pragma unroll
            for (int mt = 0; mt < 4; mt++)
                #pragma unroll
                for (int r = 0; r < 4; r++){
                    int row = mt*16 + lq*4 + r;
                    float qv = xts[row*4+0]*c0 + xts[row*4+1]*c1 + xts[row*4+2]*c2;
                    a2[row*SK + col] = f2bf_fast(accp[mt][nt][r] + qv + bb);
                }
        }
    }
    __syncthreads();
    {
        int r = tid >> 2, dq = tid & 3;
        int node = tile0 + r;
        if (node < NV){
            #pragma unroll
            for (int c = 0; c < 4; c++){
                uint4 vv = *(const uint4*)&a2[r*SK + dq*32 + c*8];
                *(uint4*)(pre_di + (size_t)node*NH + dq*32 + c*8) = vv;
            }
        }
    }

    // ---- branch s ----
    {
        short8 bfr[2][4];
        #pragma unroll
        for (int nt = 0; nt < 2; nt++)
            #pragma unroll
            for (int kc = 0; kc < 4; kc++)
                bfr[nt][kc] = *(const short8*)(wpk_next + 16384 + (colb + nt*16 + lr)*128 + kc*32 + lq*8);
        f32x4 accp[4][2];
        #pragma unroll
        for (int mt = 0; mt < 4; mt++)
            #pragma unroll
            for (int nt = 0; nt < 2; nt++) accp[mt][nt] = (f32x4){0.f,0.f,0.f,0.f};
        #pragma unroll
        for (int kc = 0; kc < 4; kc++)
            #pragma unroll
            for (int mt = 0; mt < 4; mt++){
                short8 af = *(const short8*)&a1[(mt*16 + lr)*SK + kc*32 + lq*8];
                #pragma unroll
                for (int nt = 0; nt < 2; nt++)
                    accp[mt][nt] = __builtin_amdgcn_mfma_f32_16x16x32_bf16(af, bfr[nt][kc], accp[mt][nt], 0, 0, 0);
            }
        __syncthreads();   // prior a2 store-reads done
        #pragma unroll
        for (int nt = 0; nt < 2; nt++){
            int col = colb + nt*16 + lr;
            float c0 = w1c_next[col], c1 = w1c_next[128 + col], c2 = w1c_next[256 + col];
            #pragma unroll
            for (int mt = 0; mt < 4; mt++)
                #pragma unroll
                for (int r = 0; r < 4; r++){
                    int row = mt*16 + lq*4 + r;
                    float qv = xts[row*4+0]*c0 + xts[row*4+1]*c1 + xts[row*4+2]*c2;
                    a2[row*SK + col] = f2bf_fast(accp[mt][nt][r] - qv);
                }
        }
    }
    __syncthreads();
    {
        int r = tid >> 2, dq = tid & 3;
        int node = tile0 + r;
        if (node < NV){
            bf16row_to_fp8(&a2[r*SK + dq*32], pre_sj + (size_t)node*NH + dq*32);
        }
    }
}

// ---------------- output projection + MSE (two-stage) ----------------
__global__ __launch_bounds__(256) void k_out(const float* __restrict__ h,
                                             const float* __restrict__ opw, const float* __restrict__ opb,
                                             const float* __restrict__ pos0, const float* __restrict__ pos1,
                                             float* __restrict__ partial)
{
    int v = blockIdx.x*256 + threadIdx.x;
    float sse = 0.f;
    if (v < NV){
        float v0 = opb[0], v1 = opb[1], v2 = opb[2];
        const float* hr = h + (size_t)v*NH;
        for (int k = 0; k < 128; k += 4){
            float4 hv = *(const float4*)(hr + k);
            v0 += hv.x*opw[(k+0)*3+0] + hv.y*opw[(k+1)*3+0] + hv.z*opw[(k+2)*3+0] + hv.w*opw[(k+3)*3+0];
            v1 += hv.x*opw[(k+0)*3+1] + hv.y*opw[(k+1)*3+1] + hv.z*opw[(k+2)*3+1] + hv.w*opw[(k+3)*3+1];
            v2 += hv.x*opw[(k+0)*3+2] + hv.y*opw[(k+1)*3+2] + hv.z*opw[(k+2)*3+2] + hv.w*opw[(k+3)*3+2];
        }
        float d0 = v0 - (pos1[v*3+0] - pos0[v*3+0]);
        float d1 = v1 - (pos1[v*3+1] - pos0[v*3+1]);
        float d2 = v2 - (pos1[v*3+2] - pos0[v*3+2]);
        sse = d0*d0 + d1*d1 + d2*d2;
    }
    for (int off = 32; off > 0; off >>= 1) sse += __shfl_down(sse, off, 64);
    __shared__ float red[4];
    if ((threadIdx.x & 63) == 0) red[threadIdx.x >> 6] = sse;
    __syncthreads();
    if (threadIdx.x == 0)
        partial[blockIdx.x] = red[0] + red[1] + red[2] + red[3];
}

__global__ void k_out2(const float* __restrict__ partial, float* __restrict__ out, int nparts)
{
    int tid = threadIdx.x;
    float s = (tid < nparts) ? partial[tid] : 0.f;
    for (int off = 32; off > 0; off >>= 1) s += __shfl_down(s, off, 64);
    __shared__ float red[4];
    if ((tid & 63) == 0) red[tid >> 6] = s;
    __syncthreads();
    if (tid == 0)
        out[0] = (red[0] + red[1] + red[2] + red[3]) * (1.0f/150000.0f);
}

extern "C" void kernel_launch(void* const* d_in, const int* in_sizes, int n_in,
                              void* d_out, int out_size, void* d_ws, size_t ws_size,
                              hipStream_t stream)
{
    const float* pos0  = (const float*)d_in[0];
    const float* pos1  = (const float*)d_in[1];
    const float* z     = (const float*)d_in[2];
    const float* t     = (const float*)d_in[3];
    const int*   ei    = (const int*)d_in[4];
    const int*   batch = (const int*)d_in[5];
    const float* te_w1 = (const float*)d_in[6];
    const float* te_b1 = (const float*)d_in[7];
    const float* te_w2 = (const float*)d_in[8];
    const float* te_b2 = (const float*)d_in[9];
    const float* cp_w  = (const float*)d_in[10];
    const float* cp_b  = (const float*)d_in[11];
    const float* ew1   = (const float*)d_in[12];
    const float* eb1   = (const float*)d_in[13];
    const float* ew2   = (const float*)d_in[14];
    const float* eb2   = (const float*)d_in[15];
    const float* nw1   = (const float*)d_in[16];
    const float* nb1   = (const float*)d_in[17];
    const float* nw2   = (const float*)d_in[18];
    const float* nb2   = (const float*)d_in[19];
    const float* ln_g  = (const float*)d_in[20];
    const float* ln_b  = (const float*)d_in[21];
    const float* op_w  = (const float*)d_in[22];
    const float* op_b  = (const float*)d_in[23];

    float* ws     = (float*)d_ws;
    float* tconst = ws;                        // 128
    float* zcp    = ws + 128;                  // 1024
    float* xt     = ws + 1152;                 // 150016 (NV*3 padded)
    float* h      = ws + 151168;               // NV*NH fp32
    float* agg    = h + (size_t)NV*NH;         // NV*NH fp32
    int*   ibase  = (int*)(agg + (size_t)NV*NH);
    int*   rowptr  = ibase;                    // 50016
    int*   cursor  = ibase + 50016;            // 50016
    int*   csr_eid = ibase + 100032;           // NE
    int*   csr_dst = csr_eid + NE;             // NE
    unsigned short* pre_di = (unsigned short*)(csr_dst + NE);   // NV*NH bf16
    unsigned char*  pre_sj = (unsigned char*)(pre_di + (size_t)NV*NH); // NV*NH fp8
    unsigned short* wpk    = (unsigned short*)(pre_sj + (size_t)NV*NH); // 4*6*16384 bf16
    int*   bsum   = (int*)(wpk + 4*6*16384);                    // 256 ints
    unsigned char* w2f8 = (unsigned char*)(bsum + 256);         // 4*16384 fp8
    float* outpart = (float*)(w2f8 + 4*16384);                  // 256 floats

    const int* srcrow = ei;        // edge_index[0] = src j
    const int* dstrow = ei + NE;   // edge_index[1] = dst i

    hipMemsetAsync(cursor, 0, (size_t)NV*4, stream);
    k_setup<<<1, 128, 0, stream>>>(z, t, te_w1, te_b1, te_w2, te_b2, cp_w, cp_b, tconst, zcp);
    k_init<<<(NV*NH)/256, 256, 0, stream>>>(batch, zcp, tconst, h);
    k_xt<<<(NV*3 + 255)/256, 256, 0, stream>>>(pos0, pos1, t, xt);
    k_hist<<<NE/256, 256, 0, stream>>>(dstrow, cursor);
    k_scan1<<<196, 256, 0, stream>>>(cursor, bsum);
    k_scan2<<<1, 256, 0, stream>>>(bsum);
    k_scan3<<<196, 256, 0, stream>>>(cursor, bsum, rowptr, cursor);
    k_scatter<<<NE/256, 256, 0, stream>>>(dstrow, cursor, csr_eid, csr_dst);
    k_pack_wpk<<<(4*6*16384)/256, 256, 0, stream>>>(ew1, ew2, nw1, nw2, wpk);
    k_pack_w2f8<<<(4*16384)/256, 256, 0, stream>>>(ew2, w2f8);

    for (int l = 0; l < NL; l++){
        const unsigned short* wpk_l = wpk + (size_t)l*6*16384;
        if (l == 0){
            k_pre_mfma<<<(NV + 63)/64, 256, 0, stream>>>(h, xt, wpk_l,
                                                         ew1 + 256*128, eb1,
                                                         pre_di, pre_sj, agg);
        }
        k_edge_mfma<<<NE/128, 256, 0, stream>>>(pre_di, pre_sj, csr_eid, csr_dst, srcrow, rowptr,
                                                w2f8 + (size_t)l*16384, eb2 + l*128, agg);
        int ln = (l + 1) % NL;
        const unsigned short* wpk_n = wpk + (size_t)ln*6*16384;
        const float* ew1n = ew1 + (size_t)ln*259*128;
        k_node_fused<<<(NV + 63)/64, 256, 0, stream>>>(h, agg, wpk_l + 3*16384,
                                                       nb1 + l*128, nb2 + l*128,
                                                       ln_g + l*128, ln_b + l*128,
                                                       xt, wpk_n, ew1n + 256*128, eb1 + ln*128,
                                                       pre_di, pre_sj, (l < NL-1) ? 1 : 0);
    }

    int nparts = (NV + 255)/256;   // 196
    k_out<<<nparts, 256, 0, stream>>>(h, op_w, op_b, pos0, pos1, outpart);
    k_out2<<<1, 256, 0, stream>>>(outpart, (float*)d_out, nparts);
}

// Round 15
// 897.983 us; speedup vs baseline: 1.0525x; 1.0525x over previous
//
#include <hip/hip_runtime.h>

#define NV 50000
#define NE 800000
#define NB 8
#define NH 128
#define NLAT 64
#define NTD 16
#define NL 4
#define SK 136   // LDS row stride (bf16 elems) for MFMA A tiles
#define SKB 136  // LDS row stride (bytes) for fp8 hid tile in k_edge
#define MTB 132  // LDS stride (bytes) for transposed fp8 m tile

typedef __attribute__((ext_vector_type(8))) short short8;
typedef __attribute__((ext_vector_type(4))) float f32x4;
typedef __attribute__((ext_vector_type(2))) float f32x2;

__device__ __forceinline__ float silu_f(float x){
    float e = __expf(-x);
    return x * __builtin_amdgcn_rcpf(1.0f + e);
}

// HW packed f32->bf16 convert (RNE)
__device__ __forceinline__ unsigned cvtpk(float a, float b){
    unsigned r;
    asm("v_cvt_pk_bf16_f32 %0, %1, %2" : "=v"(r) : "v"(a), "v"(b));
    return r;
}
__device__ __forceinline__ unsigned short f2bf_fast(float x){
    return (unsigned short)cvtpk(x, x);
}
// bit-twiddle fallback for one-shot pack kernel
__device__ __forceinline__ unsigned short f2bf(float x){
    unsigned u = __float_as_uint(x);
    unsigned r = (u >> 16) & 1;
    u += 0x7fffu + r;
    return (unsigned short)(u >> 16);
}
__device__ __forceinline__ float bflo(unsigned u){ return __uint_as_float(u << 16); }
__device__ __forceinline__ float bfhi(unsigned u){ return __uint_as_float(u & 0xffff0000u); }

// 32 bf16 (LDS, 16B aligned) -> 32 fp8 bytes at dstg (global)
__device__ __forceinline__ void bf16row_to_fp8(const unsigned short* src, unsigned char* dstg){
    unsigned ow[8];
    #pragma unroll
    for (int c = 0; c < 8; c++){
        uint2 uu = *(const uint2*)(src + c*4);
        unsigned w = __builtin_amdgcn_cvt_pk_fp8_f32(bflo(uu.x), bfhi(uu.x), 0, false);
        w = __builtin_amdgcn_cvt_pk_fp8_f32(bflo(uu.y), bfhi(uu.y), w, true);
        ow[c] = w;
    }
    uint4 o0, o1;
    o0.x = ow[0]; o0.y = ow[1]; o0.z = ow[2]; o0.w = ow[3];
    o1.x = ow[4]; o1.y = ow[5]; o1.z = ow[6]; o1.w = ow[7];
    *(uint4*)(dstg)      = o0;
    *(uint4*)(dstg + 16) = o1;
}

// ---------------- setup ----------------
__global__ void k_setup(const float* __restrict__ z, const float* __restrict__ t,
                        const float* __restrict__ te_w1, const float* __restrict__ te_b1,
                        const float* __restrict__ te_w2, const float* __restrict__ te_b2,
                        const float* __restrict__ cp_w, const float* __restrict__ cp_b,
                        float* __restrict__ tconst, float* __restrict__ zcp)
{
    __shared__ float hid[NTD];
    __shared__ float emb[NTD];
    int tid = threadIdx.x;
    float ts = t[0];
    if (tid < NTD) hid[tid] = silu_f(ts * te_w1[tid] + te_b1[tid]);
    __syncthreads();
    if (tid < NTD){
        float a = te_b2[tid];
        for (int j = 0; j < NTD; j++) a += hid[j] * te_w2[j*NTD + tid];
        emb[tid] = a;
    }
    __syncthreads();
    float tc = cp_b[tid];
    for (int j = 0; j < NTD; j++) tc += emb[j] * cp_w[(NLAT + j)*NH + tid];
    tconst[tid] = tc;
    for (int b = 0; b < NB; b++){
        float a = 0.f;
        for (int k = 0; k < NLAT; k++) a += z[b*NLAT + k] * cp_w[k*NH + tid];
        zcp[b*NH + tid] = a;
    }
}

__global__ void k_init(const int* __restrict__ batch, const float* __restrict__ zcp,
                       const float* __restrict__ tconst, float* __restrict__ h)
{
    int idx = blockIdx.x*256 + threadIdx.x;
    int v = idx >> 7, d = idx & 127;
    h[idx] = zcp[batch[v]*NH + d] + tconst[d];
}

__global__ void k_xt(const float* __restrict__ pos0, const float* __restrict__ pos1,
                     const float* __restrict__ t, float* __restrict__ xt)
{
    int idx = blockIdx.x*256 + threadIdx.x;
    if (idx < NV*3){
        float ts = t[0];
        xt[idx] = (1.f - ts)*pos0[idx] + ts*pos1[idx];
    }
}

// ---------------- CSR build ----------------
__global__ void k_hist(const int* __restrict__ dst, int* __restrict__ cnt)
{
    int e = blockIdx.x*256 + threadIdx.x;
    if (e < NE) atomicAdd(&cnt[dst[e]], 1);
}

__global__ void k_scan1(const int* __restrict__ deg, int* __restrict__ bsum)
{
    __shared__ int s[256];
    int tid = threadIdx.x;
    int idx = blockIdx.x*256 + tid;
    s[tid] = (idx < NV) ? deg[idx] : 0;
    __syncthreads();
    for (int off = 128; off > 0; off >>= 1){
        if (tid < off) s[tid] += s[tid + off];
        __syncthreads();
    }
    if (tid == 0) bsum[blockIdx.x] = s[0];
}

__global__ void k_scan2(int* __restrict__ bsum)
{
    __shared__ int s[256];
    int tid = threadIdx.x;
    int v = (tid < 196) ? bsum[tid] : 0;
    s[tid] = v;
    __syncthreads();
    for (int off = 1; off < 256; off <<= 1){
        int a = s[tid];
        int b = (tid >= off) ? s[tid - off] : 0;
        __syncthreads();
        s[tid] = a + b;
        __syncthreads();
    }
    if (tid < 196) bsum[tid] = (tid == 0) ? 0 : s[tid - 1];
}

__global__ void k_scan3(const int* deg, const int* __restrict__ bsum,
                        int* __restrict__ rowptr, int* cursor)
{
    __shared__ int s[256];
    int tid = threadIdx.x;
    int idx = blockIdx.x*256 + tid;
    int v = (idx < NV) ? deg[idx] : 0;
    s[tid] = v;
    __syncthreads();
    for (int off = 1; off < 256; off <<= 1){
        int a = s[tid];
        int b = (tid >= off) ? s[tid - off] : 0;
        __syncthreads();
        s[tid] = a + b;
        __syncthreads();
    }
    int excl = bsum[blockIdx.x] + ((tid == 0) ? 0 : s[tid - 1]);
    if (idx < NV){
        rowptr[idx] = excl;
        cursor[idx] = excl;
    }
    if (idx == NV - 1) rowptr[NV] = NE;
}

__global__ void k_scatter(const int* __restrict__ dst, int* __restrict__ cursor,
                          int* __restrict__ csr_eid, int* __restrict__ csr_dst)
{
    int e = blockIdx.x*256 + threadIdx.x;
    if (e < NE){
        int i = dst[e];
        int p = atomicAdd(&cursor[i], 1);
        csr_eid[p] = e;
        csr_dst[p] = i;
    }
}

// ---------------- pack weights -> bf16 [l][{eWd,eWs,eW2,nW1d,nW1a,nW2}][n][k] ----------------
__global__ void k_pack_wpk(const float* __restrict__ ew1, const float* __restrict__ ew2,
                           const float* __restrict__ nw1, const float* __restrict__ nw2,
                           unsigned short* __restrict__ wpk)
{
    int idx = blockIdx.x*256 + threadIdx.x;
    int lm = idx >> 14;
    int l = lm / 6, m = lm % 6;
    int r = idx & 16383;
    int n = r >> 7, k = r & 127;
    float v;
    if (m < 2)       v = ew1[l*33152 + (m*128 + k)*128 + n];
    else if (m == 2) v = ew2[l*16384 + k*128 + n];
    else if (m < 5)  v = nw1[l*32768 + ((m-3)*128 + k)*128 + n];
    else             v = nw2[l*16384 + k*128 + n];
    wpk[idx] = f2bf(v);
}

// ---------------- pack W2 -> fp8 [l][n][k] ----------------
__global__ void k_pack_w2f8(const float* __restrict__ ew2, unsigned char* __restrict__ w2f8)
{
    int idx = blockIdx.x*256 + threadIdx.x;        // 4*16384
    int l = idx >> 14, r = idx & 16383;
    int n = r >> 7, k = r & 127;
    float v = ew2[l*16384 + k*128 + n];
    w2f8[idx] = (unsigned char)__builtin_amdgcn_cvt_pk_fp8_f32(v, v, 0, false);
}

// ---------------- layer-0 pre-projection (MFMA, merged branches; d->bf16, s->fp8; zeroes agg) ----------------
__global__ __launch_bounds__(256) void k_pre_mfma(
    const float* __restrict__ h, const float* __restrict__ xt,
    const unsigned short* __restrict__ wpk_l,   // Wd at +0, Ws at +16384
    const float* __restrict__ w1c, const float* __restrict__ b1,
    unsigned short* __restrict__ pre_di, unsigned char* __restrict__ pre_sj,
    float* __restrict__ agg)
{
    __shared__ __align__(16) unsigned short asd[64*SK];    // A tile; reused as d-out tile
    __shared__ __align__(16) unsigned short obuf[64*SK];   // s-out tile (bf16)
    __shared__ float xts[64*4];
    int tid = threadIdx.x;
    int tile0 = blockIdx.x*64;

    {
        int r = tid >> 2, dq = tid & 3;
        int node = tile0 + r;
        bool valid = node < NV;
        const float4* hrow = (const float4*)(h + (size_t)node*NH + dq*32);
        #pragma unroll
        for (int c = 0; c < 4; c++){
            float4 v0 = valid ? hrow[c*2]     : make_float4(0.f,0.f,0.f,0.f);
            float4 v1 = valid ? hrow[c*2 + 1] : make_float4(0.f,0.f,0.f,0.f);
            uint4 o;
            o.x = cvtpk(v0.x, v0.y);
            o.y = cvtpk(v0.z, v0.w);
            o.z = cvtpk(v1.x, v1.y);
            o.w = cvtpk(v1.z, v1.w);
            *(uint4*)&asd[r*SK + dq*32 + c*8] = o;
        }
        // zero agg rows for layer-0 edge pass
        if (valid){
            float4 z4 = make_float4(0.f,0.f,0.f,0.f);
            float* ag = agg + (size_t)node*NH + dq*32;
            #pragma unroll
            for (int c = 0; c < 8; c++) *(float4*)(ag + c*4) = z4;
        }
    }
    if (tid < 64){
        int node = tile0 + tid;
        bool valid = node < NV;
        xts[tid*4+0] = valid ? xt[node*3+0] : 0.f;
        xts[tid*4+1] = valid ? xt[node*3+1] : 0.f;
        xts[tid*4+2] = valid ? xt[node*3+2] : 0.f;
        xts[tid*4+3] = 0.f;
    }

    int w = tid >> 6, l = tid & 63;
    int lr = l & 15, lq = l >> 4;

    short8 bfrd[2][4], bfrs[2][4];
    #pragma unroll
    for (int nt = 0; nt < 2; nt++)
        #pragma unroll
        for (int kc = 0; kc < 4; kc++){
            bfrd[nt][kc] = *(const short8*)(wpk_l +          (w*32 + nt*16 + lr)*128 + kc*32 + lq*8);
            bfrs[nt][kc] = *(const short8*)(wpk_l + 16384 +  (w*32 + nt*16 + lr)*128 + kc*32 + lq*8);
        }

    f32x4 accd[4][2], accs[4][2];
    #pragma unroll
    for (int mt = 0; mt < 4; mt++)
        #pragma unroll
        for (int nt = 0; nt < 2; nt++){
            accd[mt][nt] = (f32x4){0.f,0.f,0.f,0.f};
            accs[mt][nt] = (f32x4){0.f,0.f,0.f,0.f};
        }

    __syncthreads();

    #pragma unroll
    for (int kc = 0; kc < 4; kc++)
        #pragma unroll
        for (int mt = 0; mt < 4; mt++){
            short8 af = *(const short8*)&asd[(mt*16 + lr)*SK + kc*32 + lq*8];
            #pragma unroll
            for (int nt = 0; nt < 2; nt++){
                accd[mt][nt] = __builtin_amdgcn_mfma_f32_16x16x32_bf16(af, bfrd[nt][kc], accd[mt][nt], 0, 0, 0);
                accs[mt][nt] = __builtin_amdgcn_mfma_f32_16x16x32_bf16(af, bfrs[nt][kc], accs[mt][nt], 0, 0, 0);
            }
        }
    __syncthreads();

    #pragma unroll
    for (int nt = 0; nt < 2; nt++){
        int col = w*32 + nt*16 + lr;
        float c0 = w1c[col], c1 = w1c[128 + col], c2 = w1c[256 + col];
        float bb = b1[col];
        #pragma unroll
        for (int mt = 0; mt < 4; mt++){
            #pragma unroll
            for (int r = 0; r < 4; r++){
                int row = mt*16 + lq*4 + r;
                float qv = xts[row*4+0]*c0 + xts[row*4+1]*c1 + xts[row*4+2]*c2;
                asd [row*SK + col] = f2bf_fast(accd[mt][nt][r] + qv + bb);
                obuf[row*SK + col] = f2bf_fast(accs[mt][nt][r] - qv);
            }
        }
    }
    __syncthreads();

    {
        int r = tid >> 2, dq = tid & 3;
        int node = tile0 + r;
        if (node < NV){
            #pragma unroll
            for (int c = 0; c < 4; c++){
                uint4 vd = *(const uint4*)&asd[r*SK + dq*32 + c*8];
                *(uint4*)(pre_di + (size_t)node*NH + dq*32 + c*8) = vd;
            }
            bf16row_to_fp8(&obuf[r*SK + dq*32], pre_sj + (size_t)node*NH + dq*32);
        }
    }
}

// ---------------- fused edge kernel: 128-edge tiles; fp8; 2 col passes (32 AGPR) ----------------
__global__ __launch_bounds__(256) void k_edge_mfma(
    const unsigned short* __restrict__ pre_di, const unsigned char* __restrict__ pre_sj,
    const int* __restrict__ csr_eid, const int* __restrict__ csr_dst,
    const int* __restrict__ srcrow, const int* __restrict__ rowptr,
    const unsigned char* __restrict__ w2f8,   // [n][k] fp8
    const float* __restrict__ b2,
    float* __restrict__ agg)
{
    __shared__ __align__(16) unsigned char hids8[128*SKB];  // 17.4 KB fp8 hid tile
    __shared__ __align__(16) unsigned char m_t[128*MTB];    // 16.9 KB fp8 m tile (transposed)
    __shared__ int nid[128];
    __shared__ int flagL, flagR;
    __shared__ unsigned long long brk0_s, brk1_s;
    int tid = threadIdx.x;

    int b = blockIdx.x;
    int mapped = (b < 6248) ? ((b & 7)*781 + (b >> 3)) : b;
    int p0 = mapped * 128;

    if (tid == 0){
        flagL = (rowptr[csr_dst[p0]] < p0) ? 1 : 0;
        flagR = (rowptr[csr_dst[p0 + 127] + 1] > p0 + 128) ? 1 : 0;
    }

    // hid phase: di bf16 + sj fp8 -> silu -> fp8 LDS
    #pragma unroll
    for (int sub = 0; sub < 2; sub++){
        int el = sub*64 + (tid >> 2), q = tid & 3;
        int p = p0 + el;
        int eid = csr_eid[p];
        int iN  = csr_dst[p];
        int jN  = srcrow[eid];
        if (q == 0) nid[el] = iN;
        const uint4* gd = (const uint4*)(pre_di + (size_t)iN*NH + q*32);
        const uint4* gs = (const uint4*)(pre_sj + (size_t)jN*NH + q*32);
        uint4 s0 = gs[0], s1 = gs[1];
        unsigned sw[8] = {s0.x, s0.y, s0.z, s0.w, s1.x, s1.y, s1.z, s1.w};
        #pragma unroll
        for (int c = 0; c < 4; c++){
            uint4 a = gd[c];
            unsigned au[4] = {a.x, a.y, a.z, a.w};
            f32x2 pa = __builtin_amdgcn_cvt_pk_f32_fp8(sw[c*2],   false);
            f32x2 pb = __builtin_amdgcn_cvt_pk_f32_fp8(sw[c*2],   true);
            f32x2 pc = __builtin_amdgcn_cvt_pk_f32_fp8(sw[c*2+1], false);
            f32x2 pd = __builtin_amdgcn_cvt_pk_f32_fp8(sw[c*2+1], true);
            float sv[8] = {pa.x, pa.y, pb.x, pb.y, pc.x, pc.y, pd.x, pd.y};
            float lo0 = silu_f(bflo(au[0]) + sv[0]);
            float hi0 = silu_f(bfhi(au[0]) + sv[1]);
            float lo1 = silu_f(bflo(au[1]) + sv[2]);
            float hi1 = silu_f(bfhi(au[1]) + sv[3]);
            float lo2 = silu_f(bflo(au[2]) + sv[4]);
            float hi2 = silu_f(bfhi(au[2]) + sv[5]);
            float lo3 = silu_f(bflo(au[3]) + sv[6]);
            float hi3 = silu_f(bfhi(au[3]) + sv[7]);
            unsigned w0 = __builtin_amdgcn_cvt_pk_fp8_f32(lo0, hi0, 0, false);
            w0 = __builtin_amdgcn_cvt_pk_fp8_f32(lo1, hi1, w0, true);
            unsigned w1 = __builtin_amdgcn_cvt_pk_fp8_f32(lo2, hi2, 0, false);
            w1 = __builtin_amdgcn_cvt_pk_fp8_f32(lo3, hi3, w1, true);
            uint2 o; o.x = w0; o.y = w1;
            *(uint2*)&hids8[el*SKB + q*32 + c*8] = o;
        }
    }

    int w = tid >> 6, l = tid & 63;
    int lr = l & 15, lq = l >> 4;
    // B frags for both col passes: pass p covers cols p*64 + w*16 + lr
    long bfr[2][4];
    #pragma unroll
    for (int pass = 0; pass < 2; pass++)
        #pragma unroll
        for (int kc = 0; kc < 4; kc++)
            bfr[pass][kc] = *(const long*)(w2f8 + (pass*64 + w*16 + lr)*128 + kc*32 + lq*8);

    __syncthreads();

    if (tid < 64){
        bool bb = (tid > 0) && (nid[tid] != nid[tid - 1]);
        unsigned long long mask = __ballot(bb);
        if (tid == 0) brk0_s = mask;
    } else if (tid < 128){
        int lane = tid - 64;
        bool bb = (nid[64 + lane] != nid[63 + lane]);
        unsigned long long mask = __ballot(bb);
        if (lane == 0) brk1_s = mask;
    }

    // two column passes, 32 AGPRs each, epilogue straight to m_t (separate buffer, no barrier)
    #pragma unroll
    for (int pass = 0; pass < 2; pass++){
        f32x4 acc[8];
        #pragma unroll
        for (int mt = 0; mt < 8; mt++) acc[mt] = (f32x4){0.f,0.f,0.f,0.f};
        #pragma unroll
        for (int kc = 0; kc < 4; kc++){
            #pragma unroll
            for (int mt = 0; mt < 8; mt++){
                long af = *(const long*)&hids8[(mt*16 + lr)*SKB + kc*32 + lq*8];
                acc[mt] = __builtin_amdgcn_mfma_f32_16x16x32_fp8_fp8(af, bfr[pass][kc], acc[mt], 0, 0, 0);
            }
        }
        int col = pass*64 + w*16 + lr;
        float bv = b2[col];
        #pragma unroll
        for (int mt = 0; mt < 8; mt++){
            float v0 = silu_f(acc[mt][0] + bv);
            float v1 = silu_f(acc[mt][1] + bv);
            float v2 = silu_f(acc[mt][2] + bv);
            float v3 = silu_f(acc[mt][3] + bv);
            unsigned wv = __builtin_amdgcn_cvt_pk_fp8_f32(v0, v1, 0, false);
            wv = __builtin_amdgcn_cvt_pk_fp8_f32(v2, v3, wv, true);
            *(unsigned*)&m_t[col*MTB + mt*16 + lq*4] = wv;
        }
    }
    __syncthreads();

    {
        int half = tid >> 7, d = tid & 127;
        int r0 = half * 64;
        bool junc = !((brk1_s) & 1ull);
        unsigned long long m2 = half ? (brk1_s & ~1ull) : brk0_s;
        bool leftCont  = half ? junc : (flagL != 0);
        bool rightCont = half ? (flagR != 0) : junc;

        float run = 0.f;
        int curn = nid[r0];
        bool firstRun = true;
        const unsigned char* mrow = m_t + d*MTB;

        #pragma unroll
        for (int g = 0; g < 16; g++){
            int row = r0 + g*4;
            unsigned v = *(const unsigned*)&mrow[row];
            f32x2 pa = __builtin_amdgcn_cvt_pk_f32_fp8(v, false);
            f32x2 pb = __builtin_amdgcn_cvt_pk_f32_fp8(v, true);
            float f0 = pa.x, f1 = pa.y, f2 = pb.x, f3 = pb.y;
            unsigned gm = (unsigned)((m2 >> (g*4)) & 0xFull);
            if (gm == 0u){
                run += (f0 + f1) + (f2 + f3);
            } else {
                float fv[4] = {f0, f1, f2, f3};
                #pragma unroll
                for (int r = 0; r < 4; r++){
                    if (gm & (1u << r)){
                        bool at = firstRun && leftCont;
                        if (at) atomicAdd(&agg[(size_t)curn*NH + d], run);
                        else    agg[(size_t)curn*NH + d] = run;
                        firstRun = false;
                        run = 0.f;
                        curn = nid[row + r];
                    }
                    run += fv[r];
                }
            }
        }
        bool at = (firstRun && leftCont) || rightCont;
        if (at) atomicAdd(&agg[(size_t)curn*NH + d], run);
        else    agg[(size_t)curn*NH + d] = run;
    }
}

// ---------------- fused node kernel: LN(h + MLP([h|agg])) then next-layer pre; re-zeroes agg ----------------
__global__ __launch_bounds__(256) void k_node_fused(
    float* __restrict__ h, float* __restrict__ agg,
    const unsigned short* __restrict__ wn,   // node weights: W1d, W1a, W2
    const float* __restrict__ b1, const float* __restrict__ b2,
    const float* __restrict__ g, const float* __restrict__ bta,
    const float* __restrict__ xt,
    const unsigned short* __restrict__ wpk_next,   // next-layer eWd at +0, eWs at +16384
    const float* __restrict__ w1c_next, const float* __restrict__ b1_next,
    unsigned short* __restrict__ pre_di, unsigned char* __restrict__ pre_sj,
    int do_pre)
{
    __shared__ __align__(16) unsigned short abuf[2*64*SK];
    __shared__ float ps[64][4], pq[64][4];
    __shared__ float mu_s[64], rs_s[64];
    __shared__ float xts[64*4];
    int tid = threadIdx.x;
    int tile0 = blockIdx.x*64;
    unsigned short* a1 = abuf;
    unsigned short* a2 = abuf + 64*SK;

    {
        int r = tid >> 2, dq = tid & 3;
        int node = tile0 + r;
        bool valid = node < NV;
        const float4* hrow = (const float4*)(h   + (size_t)node*NH + dq*32);
        const float4* arow = (const float4*)(agg + (size_t)node*NH + dq*32);
        #pragma unroll
        for (int c = 0; c < 4; c++){
            float4 v0 = valid ? hrow[c*2]     : make_float4(0.f,0.f,0.f,0.f);
            float4 v1 = valid ? hrow[c*2 + 1] : make_float4(0.f,0.f,0.f,0.f);
            float4 u0 = valid ? arow[c*2]     : make_float4(0.f,0.f,0.f,0.f);
            float4 u1 = valid ? arow[c*2 + 1] : make_float4(0.f,0.f,0.f,0.f);
            uint4 o;
            o.x = cvtpk(v0.x, v0.y); o.y = cvtpk(v0.z, v0.w);
            o.z = cvtpk(v1.x, v1.y); o.w = cvtpk(v1.z, v1.w);
            *(uint4*)&a1[r*SK + dq*32 + c*8] = o;
            uint4 p;
            p.x = cvtpk(u0.x, u0.y); p.y = cvtpk(u0.z, u0.w);
            p.z = cvtpk(u1.x, u1.y); p.w = cvtpk(u1.z, u1.w);
            *(uint4*)&a2[r*SK + dq*32 + c*8] = p;
        }
        // re-zero agg for the next layer's edge pass (only if one follows)
        if (do_pre && valid){
            float4 z4 = make_float4(0.f,0.f,0.f,0.f);
            float* ag = agg + (size_t)node*NH + dq*32;
            #pragma unroll
            for (int c = 0; c < 8; c++) *(float4*)(ag + c*4) = z4;
        }
    }
    if (tid < 64){
        int node = tile0 + tid;
        bool valid = node < NV;
        xts[tid*4+0] = valid ? xt[node*3+0] : 0.f;
        xts[tid*4+1] = valid ? xt[node*3+1] : 0.f;
        xts[tid*4+2] = valid ? xt[node*3+2] : 0.f;
        xts[tid*4+3] = 0.f;
    }

    int w = tid >> 6, l = tid & 63;
    int lr = l & 15, lq = l >> 4;
    int colb = w*32;

    __syncthreads();

    f32x4 acc[4][2];
    #pragma unroll
    for (int mt = 0; mt < 4; mt++)
        #pragma unroll
        for (int nt = 0; nt < 2; nt++) acc[mt][nt] = (f32x4){0.f,0.f,0.f,0.f};

    {
        short8 bfr[2][4];
        #pragma unroll
        for (int nt = 0; nt < 2; nt++)
            #pragma unroll
            for (int kc = 0; kc < 4; kc++)
                bfr[nt][kc] = *(const short8*)(wn + (colb + nt*16 + lr)*128 + kc*32 + lq*8);
        #pragma unroll
        for (int kc = 0; kc < 4; kc++)
            #pragma unroll
            for (int mt = 0; mt < 4; mt++){
                short8 af = *(const short8*)&a1[(mt*16 + lr)*SK + kc*32 + lq*8];
                #pragma unroll
                for (int nt = 0; nt < 2; nt++)
                    acc[mt][nt] = __builtin_amdgcn_mfma_f32_16x16x32_bf16(af, bfr[nt][kc], acc[mt][nt], 0, 0, 0);
            }
    }
    {
        short8 bfr[2][4];
        #pragma unroll
        for (int nt = 0; nt < 2; nt++)
            #pragma unroll
            for (int kc = 0; kc < 4; kc++)
                bfr[nt][kc] = *(const short8*)(wn + 16384 + (colb + nt*16 + lr)*128 + kc*32 + lq*8);
        #pragma unroll
        for (int kc = 0; kc < 4; kc++)
            #pragma unroll
            for (int mt = 0; mt < 4; mt++){
                short8 af = *(const short8*)&a2[(mt*16 + lr)*SK + kc*32 + lq*8];
                #pragma unroll
                for (int nt = 0; nt < 2; nt++)
                    acc[mt][nt] = __builtin_amdgcn_mfma_f32_16x16x32_bf16(af, bfr[nt][kc], acc[mt][nt], 0, 0, 0);
            }
    }
    __syncthreads();

    #pragma unroll
    for (int nt = 0; nt < 2; nt++){
        int col = colb + nt*16 + lr;
        float bv = b1[col];
        #pragma unroll
        for (int mt = 0; mt < 4; mt++)
            #pragma unroll
            for (int r = 0; r < 4; r++){
                int row = mt*16 + lq*4 + r;
                a1[row*SK + col] = f2bf_fast(silu_f(acc[mt][nt][r] + bv));
            }
    }
    __syncthreads();

    f32x4 acc2[4][2];
    #pragma unroll
    for (int mt = 0; mt < 4; mt++)
        #pragma unroll
        for (int nt = 0; nt < 2; nt++) acc2[mt][nt] = (f32x4){0.f,0.f,0.f,0.f};
    {
        short8 bfr[2][4];
        #pragma unroll
        for (int nt = 0; nt < 2; nt++)
            #pragma unroll
            for (int kc = 0; kc < 4; kc++)
                bfr[nt][kc] = *(const short8*)(wn + 2*16384 + (colb + nt*16 + lr)*128 + kc*32 + lq*8);
        #pragma unroll
        for (int kc = 0; kc < 4; kc++)
            #pragma unroll
            for (int mt = 0; mt < 4; mt++){
                short8 af = *(const short8*)&a1[(mt*16 + lr)*SK + kc*32 + lq*8];
                #pragma unroll
                for (int nt = 0; nt < 2; nt++)
                    acc2[mt][nt] = __builtin_amdgcn_mfma_f32_16x16x32_bf16(af, bfr[nt][kc], acc2[mt][nt], 0, 0, 0);
            }
    }
    __syncthreads();

    float* xls = (float*)abuf;
    #pragma unroll
    for (int nt = 0; nt < 2; nt++){
        int col = colb + nt*16 + lr;
        float bv = b2[col];
        #pragma unroll
        for (int mt = 0; mt < 4; mt++)
            #pragma unroll
            for (int r = 0; r < 4; r++){
                int row = mt*16 + lq*4 + r;
                int node = tile0 + row;
                float hv = (node < NV) ? h[(size_t)node*NH + col] : 0.f;
                xls[row*132 + col] = hv + acc2[mt][nt][r] + bv;
            }
    }
    __syncthreads();

    {
        int r = tid >> 2, part = tid & 3;
        float s = 0.f, q = 0.f;
        #pragma unroll 8
        for (int i = 0; i < 32; i++){
            float x = xls[r*132 + part*32 + i];
            s += x; q += x*x;
        }
        ps[r][part] = s; pq[r][part] = q;
    }
    __syncthreads();
    if (tid < 64){
        float s = ps[tid][0] + ps[tid][1] + ps[tid][2] + ps[tid][3];
        float q = pq[tid][0] + pq[tid][1] + pq[tid][2] + pq[tid][3];
        float mu = s * (1.f/128.f);
        float var = q * (1.f/128.f) - mu*mu;
        mu_s[tid] = mu;
        rs_s[tid] = rsqrtf(var + 1e-5f);
    }
    __syncthreads();

    float ovals[32];
    {
        int r = tid >> 2, part = tid & 3;
        int node = tile0 + r;
        float mu = mu_s[r], rs = rs_s[r];
        #pragma unroll
        for (int c = 0; c < 8; c++){
            int d = part*32 + c*4;
            float4 o;
            o.x = g[d+0]*(xls[r*132 + d+0] - mu)*rs + bta[d+0];
            o.y = g[d+1]*(xls[r*132 + d+1] - mu)*rs + bta[d+1];
            o.z = g[d+2]*(xls[r*132 + d+2] - mu)*rs + bta[d+2];
            o.w = g[d+3]*(xls[r*132 + d+3] - mu)*rs + bta[d+3];
            ovals[c*4+0] = o.x; ovals[c*4+1] = o.y;
            ovals[c*4+2] = o.z; ovals[c*4+3] = o.w;
            if (node < NV) *(float4*)(h + (size_t)node*NH + d) = o;
        }
    }

    if (!do_pre) return;

    __syncthreads();   // all xls reads done -> abuf reusable
    // pack LN result -> a1 (bf16 A-tile)
    {
        int r = tid >> 2, part = tid & 3;
        #pragma unroll
        for (int c = 0; c < 4; c++){
            uint4 o;
            o.x = cvtpk(ovals[c*8+0], ovals[c*8+1]);
            o.y = cvtpk(ovals[c*8+2], ovals[c*8+3]);
            o.z = cvtpk(ovals[c*8+4], ovals[c*8+5]);
            o.w = cvtpk(ovals[c*8+6], ovals[c*8+7]);
            *(uint4*)&a1[r*SK + part*32 + c*8] = o;
        }
    }

    // B frags for both branches
    short8 bfrd[2][4], bfrs[2][4];
    #pragma unroll
    for (int nt = 0; nt < 2; nt++)
        #pragma unroll
        for (int kc = 0; kc < 4; kc++){
            bfrd[nt][kc] = *(const short8*)(wpk_next +         (colb + nt*16 + lr)*128 + kc*32 + lq*8);
            bfrs[nt][kc] = *(const short8*)(wpk_next + 16384 + (colb + nt*16 + lr)*128 + kc*32 + lq*8);
        }

    f32x4 accd[4][2], accs[4][2];
    #pragma unroll
    for (int mt = 0; mt < 4; mt++)
        #pragma unroll
        for (int nt = 0; nt < 2; nt++){
            accd[mt][nt] = (f32x4){0.f,0.f,0.f,0.f};
            accs[mt][nt] = (f32x4){0.f,0.f,0.f,0.f};
        }

    __syncthreads();

    #pragma unroll
    for (int kc = 0; kc < 4; kc++)
        #pragma unroll
        for (int mt = 0; mt < 4; mt++){
            short8 af = *(const short8*)&a1[(mt*16 + lr)*SK + kc*32 + lq*8];
            #pragma unroll
            for (int nt = 0; nt < 2; nt++){
                accd[mt][nt] = __builtin_amdgcn_mfma_f32_16x16x32_bf16(af, bfrd[nt][kc], accd[mt][nt], 0, 0, 0);
                accs[mt][nt] = __builtin_amdgcn_mfma_f32_16x16x32_bf16(af, bfrs[nt][kc], accs[mt][nt], 0, 0, 0);
            }
        }

    // epilogue d -> a2 (a2 region free: xls reads done)
    #pragma unroll
    for (int nt = 0; nt < 2; nt++){
        int col = colb + nt*16 + lr;
        float c0 = w1c_next[col], c1 = w1c_next[128 + col], c2 = w1c_next[256 + col];
        float bb = b1_next[col];
        #pragma unroll
        for (int mt = 0; mt < 4; mt++)
            #pragma unroll
            for (int r = 0; r < 4; r++){
                int row = mt*16 + lq*4 + r;
                float qv = xts[row*4+0]*c0 + xts[row*4+1]*c1 + xts[row*4+2]*c2;
                a2[row*SK + col] = f2bf_fast(accd[mt][nt][r] + qv + bb);
            }
    }
    __syncthreads();   // d-tile visible; all a1 GEMM reads complete

    // store d from a2; epilogue s -> a1
    {
        int r = tid >> 2, dq = tid & 3;
        int node = tile0 + r;
        if (node < NV){
            #pragma unroll
            for (int c = 0; c < 4; c++){
                uint4 vv = *(const uint4*)&a2[r*SK + dq*32 + c*8];
                *(uint4*)(pre_di + (size_t)node*NH + dq*32 + c*8) = vv;
            }
        }
    }
    #pragma unroll
    for (int nt = 0; nt < 2; nt++){
        int col = colb + nt*16 + lr;
        float c0 = w1c_next[col], c1 = w1c_next[128 + col], c2 = w1c_next[256 + col];
        #pragma unroll
        for (int mt = 0; mt < 4; mt++)
            #pragma unroll
            for (int r = 0; r < 4; r++){
                int row = mt*16 + lq*4 + r;
                float qv = xts[row*4+0]*c0 + xts[row*4+1]*c1 + xts[row*4+2]*c2;
                a1[row*SK + col] = f2bf_fast(accs[mt][nt][r] - qv);
            }
    }
    __syncthreads();

    // store s from a1 (fp8 convert)
    {
        int r = tid >> 2, dq = tid & 3;
        int node = tile0 + r;
        if (node < NV){
            bf16row_to_fp8(&a1[r*SK + dq*32], pre_sj + (size_t)node*NH + dq*32);
        }
    }
}

// ---------------- output projection + MSE (two-stage) ----------------
__global__ __launch_bounds__(256) void k_out(const float* __restrict__ h,
                                             const float* __restrict__ opw, const float* __restrict__ opb,
                                             const float* __restrict__ pos0, const float* __restrict__ pos1,
                                             float* __restrict__ partial)
{
    int v = blockIdx.x*256 + threadIdx.x;
    float sse = 0.f;
    if (v < NV){
        float v0 = opb[0], v1 = opb[1], v2 = opb[2];
        const float* hr = h + (size_t)v*NH;
        for (int k = 0; k < 128; k += 4){
            float4 hv = *(const float4*)(hr + k);
            v0 += hv.x*opw[(k+0)*3+0] + hv.y*opw[(k+1)*3+0] + hv.z*opw[(k+2)*3+0] + hv.w*opw[(k+3)*3+0];
            v1 += hv.x*opw[(k+0)*3+1] + hv.y*opw[(k+1)*3+1] + hv.z*opw[(k+2)*3+1] + hv.w*opw[(k+3)*3+1];
            v2 += hv.x*opw[(k+0)*3+2] + hv.y*opw[(k+1)*3+2] + hv.z*opw[(k+2)*3+2] + hv.w*opw[(k+3)*3+2];
        }
        float d0 = v0 - (pos1[v*3+0] - pos0[v*3+0]);
        float d1 = v1 - (pos1[v*3+1] - pos0[v*3+1]);
        float d2 = v2 - (pos1[v*3+2] - pos0[v*3+2]);
        sse = d0*d0 + d1*d1 + d2*d2;
    }
    for (int off = 32; off > 0; off >>= 1) sse += __shfl_down(sse, off, 64);
    __shared__ float red[4];
    if ((threadIdx.x & 63) == 0) red[threadIdx.x >> 6] = sse;
    __syncthreads();
    if (threadIdx.x == 0)
        partial[blockIdx.x] = red[0] + red[1] + red[2] + red[3];
}

__global__ void k_out2(const float* __restrict__ partial, float* __restrict__ out, int nparts)
{
    int tid = threadIdx.x;
    float s = (tid < nparts) ? partial[tid] : 0.f;
    for (int off = 32; off > 0; off >>= 1) s += __shfl_down(s, off, 64);
    __shared__ float red[4];
    if ((tid & 63) == 0) red[tid >> 6] = s;
    __syncthreads();
    if (tid == 0)
        out[0] = (red[0] + red[1] + red[2] + red[3]) * (1.0f/150000.0f);
}

extern "C" void kernel_launch(void* const* d_in, const int* in_sizes, int n_in,
                              void* d_out, int out_size, void* d_ws, size_t ws_size,
                              hipStream_t stream)
{
    const float* pos0  = (const float*)d_in[0];
    const float* pos1  = (const float*)d_in[1];
    const float* z     = (const float*)d_in[2];
    const float* t     = (const float*)d_in[3];
    const int*   ei    = (const int*)d_in[4];
    const int*   batch = (const int*)d_in[5];
    const float* te_w1 = (const float*)d_in[6];
    const float* te_b1 = (const float*)d_in[7];
    const float* te_w2 = (const float*)d_in[8];
    const float* te_b2 = (const float*)d_in[9];
    const float* cp_w  = (const float*)d_in[10];
    const float* cp_b  = (const float*)d_in[11];
    const float* ew1   = (const float*)d_in[12];
    const float* eb1   = (const float*)d_in[13];
    const float* ew2   = (const float*)d_in[14];
    const float* eb2   = (const float*)d_in[15];
    const float* nw1   = (const float*)d_in[16];
    const float* nb1   = (const float*)d_in[17];
    const float* nw2   = (const float*)d_in[18];
    const float* nb2   = (const float*)d_in[19];
    const float* ln_g  = (const float*)d_in[20];
    const float* ln_b  = (const float*)d_in[21];
    const float* op_w  = (const float*)d_in[22];
    const float* op_b  = (const float*)d_in[23];

    float* ws     = (float*)d_ws;
    float* tconst = ws;                        // 128
    float* zcp    = ws + 128;                  // 1024
    float* xt     = ws + 1152;                 // 150016 (NV*3 padded)
    float* h      = ws + 151168;               // NV*NH fp32
    float* agg    = h + (size_t)NV*NH;         // NV*NH fp32
    int*   ibase  = (int*)(agg + (size_t)NV*NH);
    int*   rowptr  = ibase;                    // 50016
    int*   cursor  = ibase + 50016;            // 50016
    int*   csr_eid = ibase + 100032;           // NE
    int*   csr_dst = csr_eid + NE;             // NE
    unsigned short* pre_di = (unsigned short*)(csr_dst + NE);   // NV*NH bf16
    unsigned char*  pre_sj = (unsigned char*)(pre_di + (size_t)NV*NH); // NV*NH fp8
    unsigned short* wpk    = (unsigned short*)(pre_sj + (size_t)NV*NH); // 4*6*16384 bf16
    int*   bsum   = (int*)(wpk + 4*6*16384);                    // 256 ints
    unsigned char* w2f8 = (unsigned char*)(bsum + 256);         // 4*16384 fp8
    float* outpart = (float*)(w2f8 + 4*16384);                  // 256 floats

    const int* srcrow = ei;        // edge_index[0] = src j
    const int* dstrow = ei + NE;   // edge_index[1] = dst i

    hipMemsetAsync(cursor, 0, (size_t)NV*4, stream);
    k_setup<<<1, 128, 0, stream>>>(z, t, te_w1, te_b1, te_w2, te_b2, cp_w, cp_b, tconst, zcp);
    k_init<<<(NV*NH)/256, 256, 0, stream>>>(batch, zcp, tconst, h);
    k_xt<<<(NV*3 + 255)/256, 256, 0, stream>>>(pos0, pos1, t, xt);
    k_hist<<<NE/256, 256, 0, stream>>>(dstrow, cursor);
    k_scan1<<<196, 256, 0, stream>>>(cursor, bsum);
    k_scan2<<<1, 256, 0, stream>>>(bsum);
    k_scan3<<<196, 256, 0, stream>>>(cursor, bsum, rowptr, cursor);
    k_scatter<<<NE/256, 256, 0, stream>>>(dstrow, cursor, csr_eid, csr_dst);
    k_pack_wpk<<<(4*6*16384)/256, 256, 0, stream>>>(ew1, ew2, nw1, nw2, wpk);
    k_pack_w2f8<<<(4*16384)/256, 256, 0, stream>>>(ew2, w2f8);

    for (int l = 0; l < NL; l++){
        const unsigned short* wpk_l = wpk + (size_t)l*6*16384;
        if (l == 0){
            k_pre_mfma<<<(NV + 63)/64, 256, 0, stream>>>(h, xt, wpk_l,
                                                         ew1 + 256*128, eb1,
                                                         pre_di, pre_sj, agg);
        }
        k_edge_mfma<<<NE/128, 256, 0, stream>>>(pre_di, pre_sj, csr_eid, csr_dst, srcrow, rowptr,
                                                w2f8 + (size_t)l*16384, eb2 + l*128, agg);
        int ln = (l + 1) % NL;
        const unsigned short* wpk_n = wpk + (size_t)ln*6*16384;
        const float* ew1n = ew1 + (size_t)ln*259*128;
        k_node_fused<<<(NV + 63)/64, 256, 0, stream>>>(h, agg, wpk_l + 3*16384,
                                                       nb1 + l*128, nb2 + l*128,
                                                       ln_g + l*128, ln_b + l*128,
                                                       xt, wpk_n, ew1n + 256*128, eb1 + ln*128,
                                                       pre_di, pre_sj, (l < NL-1) ? 1 : 0);
    }

    int nparts = (NV + 255)/256;   // 196
    k_out<<<nparts, 256, 0, stream>>>(h, op_w, op_b, pos0, pos1, outpart);
    k_out2<<<1, 256, 0, stream>>>(outpart, (float*)d_out, nparts);
}